// Round 1
// baseline (292.331 us; speedup 1.0000x reference)
//
#include <hip/hip_runtime.h>
#include <math.h>

// Problem constants (from reference)
#define Bdim   32768
#define Ndim   64
#define K0dim  8
#define KSH    2
#define KT     10          // K0 + SHARED
#define BN     (Bdim * Ndim)
#define DELTA  1e-06f
// log(1 - 1e-6)
#define LOG1MD (-1.0000005000001665e-06f)

// stable log(1+exp(t))
__device__ __forceinline__ float log1pexp(float t) {
    float e = __expf(-fabsf(t));
    return fmaxf(t, 0.0f) + __logf(1.0f + e);
}

__global__ __launch_bounds__(256) void sigmoid_flow_kernel(
    const float* __restrict__ x,
    const float* __restrict__ logdet,
    const float* __restrict__ dsp,     // (B, N, 3, K0) contiguous: 24 floats / point
    const float* __restrict__ shp,     // (1, N, 3, KSH): N*6 floats
    float* __restrict__ out)           // [0,BN): xnew ; [BN,2BN): logdet_out
{
    __shared__ float s_sh[Ndim * 6];   // 384 floats
    for (int t = threadIdx.x; t < Ndim * 6; t += blockDim.x) s_sh[t] = shp[t];
    __syncthreads();

    int idx = blockIdx.x * blockDim.x + threadIdx.x;   // grid sized exactly
    float xv = x[idx];
    float ld = logdet[idx];
    int n = idx & (Ndim - 1);

    // 6 x float4 = 24 floats: rows [a(8) | b(8) | w_logits(8)]
    const float4* p = (const float4*)(dsp + (size_t)idx * 24);
    float4 r0 = p[0], r1 = p[1];   // a params
    float4 r2 = p[2], r3 = p[3];   // b params
    float4 r4 = p[4], r5 = p[5];   // w logits

    float ap[KT], bp[KT], wl[KT];
    ap[0]=r0.x; ap[1]=r0.y; ap[2]=r0.z; ap[3]=r0.w;
    ap[4]=r1.x; ap[5]=r1.y; ap[6]=r1.z; ap[7]=r1.w;
    bp[0]=r2.x; bp[1]=r2.y; bp[2]=r2.z; bp[3]=r2.w;
    bp[4]=r3.x; bp[5]=r3.y; bp[6]=r3.z; bp[7]=r3.w;
    wl[0]=r4.x; wl[1]=r4.y; wl[2]=r4.z; wl[3]=r4.w;
    wl[4]=r5.x; wl[5]=r5.y; wl[6]=r5.z; wl[7]=r5.w;

    const float* sh = &s_sh[n * 6];
    ap[8] = sh[0]; ap[9] = sh[1];
    bp[8] = sh[2]; bp[9] = sh[3];
    wl[8] = sh[4]; wl[9] = sh[5];

    // softmax over w logits (K=10)
    float wmax = wl[0];
    #pragma unroll
    for (int k = 1; k < KT; ++k) wmax = fmaxf(wmax, wl[k]);
    float wexp[KT];
    float wsum = 0.0f;
    #pragma unroll
    for (int k = 0; k < KT; ++k) { wexp[k] = __expf(wl[k] - wmax); wsum += wexp[k]; }
    float inv_wsum = __fdividef(1.0f, wsum);
    float lwsum = __logf(wsum);

    float x_pre = 0.0f;
    float lj[KT];
    float ljmax = -3.0e38f;
    #pragma unroll
    for (int k = 0; k < KT; ++k) {
        float a   = log1pexp(ap[k]) + 0.001f;       // _softplus
        float pre = fmaf(a, xv, bp[k]);
        float e    = __expf(-fabsf(pre));
        float l1pe = __logf(1.0f + e);
        float sig  = ((pre >= 0.0f) ? 1.0f : e) * __fdividef(1.0f, 1.0f + e);
        x_pre += wexp[k] * sig;
        // _logsigmoid(pre) + _logsigmoid(-pre) = -(|pre| + 2*log1p(e)) - 0.002
        float lss = -(fabsf(pre) + 2.0f * l1pe) - 0.002f;
        // defer the constant (-wmax - lwsum) of log_softmax
        float v = wl[k] + lss + __logf(a);
        lj[k] = v;
        ljmax = fmaxf(ljmax, v);
    }
    x_pre *= inv_wsum;

    float es = 0.0f;
    #pragma unroll
    for (int k = 0; k < KT; ++k) es += __expf(lj[k] - ljmax);
    float lse = ljmax + __logf(es) - wmax - lwsum;   // logsumexp(logj)

    float xc   = x_pre * (1.0f - DELTA) + DELTA * 0.5f;
    float lxc  = __logf(xc);
    float l1xc = __logf(1.0f - xc);

    out[idx]      = lxc - l1xc;                               // xnew
    out[BN + idx] = ld + lse + LOG1MD - (lxc + l1xc);         // logdet_out
}

extern "C" void kernel_launch(void* const* d_in, const int* in_sizes, int n_in,
                              void* d_out, int out_size, void* d_ws, size_t ws_size,
                              hipStream_t stream) {
    const float* x   = (const float*)d_in[0];
    const float* ld  = (const float*)d_in[1];
    const float* dsp = (const float*)d_in[2];
    const float* shp = (const float*)d_in[3];
    float* out = (float*)d_out;

    const int block = 256;
    const int grid  = BN / block;   // 2097152 / 256 = 8192, exact
    sigmoid_flow_kernel<<<grid, block, 0, stream>>>(x, ld, dsp, shp, out);
}

// Round 2
// 291.344 us; speedup vs baseline: 1.0034x; 1.0034x over previous
//
#include <hip/hip_runtime.h>
#include <math.h>

// Problem constants (from reference)
#define Bdim   32768
#define Ndim   64
#define KT     10                 // K0(8) + SHARED(2)
#define BN     (Bdim * Ndim)
#define DELTA  1e-06f
#define LOG1MD (-1.0000005000001665e-06f)   // log(1 - 1e-6)

#define PTS    256                // points per block (= blockDim.x)
#define LSTR   25                 // padded LDS stride (24+1): stride-25 reads hit all 32 banks

__global__ __launch_bounds__(256) void sigmoid_flow_kernel(
    const float* __restrict__ x,
    const float* __restrict__ logdet,
    const float* __restrict__ dsp,     // (B, N, 3, 8): 24 contiguous floats per point
    const float* __restrict__ shp,     // (1, N, 3, 2): 384 floats
    float* __restrict__ out)           // [0,BN): xnew ; [BN,2BN): logdet_out
{
    __shared__ float s[PTS * LSTR];    // 25600 B: per-point params, padded
    __shared__ float s_sh[Ndim * 6];   // 1536 B: shared params

    const int t = threadIdx.x;

    // stage shared params (384 floats, 2 coalesced rounds)
    for (int i = t; i < Ndim * 6; i += PTS) s_sh[i] = shp[i];

    // stage this block's dsparams slab: 256 points * 24 floats = 1536 float4,
    // perfectly coalesced; scatter into padded point-major LDS layout.
    const float4* g = (const float4*)dsp + (size_t)blockIdx.x * (PTS * 6);
    #pragma unroll
    for (int j = 0; j < 6; ++j) {
        int q = t + PTS * j;           // float4 index within slab, coalesced
        float4 v = g[q];
        int f  = q * 4;                // flat float index within slab
        int pt = f / 24;               // point within block (magic-mul div)
        int pm = f - pt * 24;          // 0,4,8,...,20 — never crosses a point
        float* d = &s[pt * LSTR + pm];
        d[0] = v.x; d[1] = v.y; d[2] = v.z; d[3] = v.w;
    }
    __syncthreads();

    const int idx = blockIdx.x * PTS + t;
    const float xv = x[idx];
    const float ld = logdet[idx];

    const float* m  = &s[t * LSTR];          // this thread's 24 params
    const float* sh = &s_sh[(t & 63) * 6];   // n = idx % 64 == t % 64

    float ap[KT], bp[KT], wl[KT];
    #pragma unroll
    for (int k = 0; k < 8; ++k) {
        ap[k] = m[k]; bp[k] = m[8 + k]; wl[k] = m[16 + k];
    }
    ap[8] = sh[0]; ap[9] = sh[1];
    bp[8] = sh[2]; bp[9] = sh[3];
    wl[8] = sh[4]; wl[9] = sh[5];

    // Linear-domain fused pass. Per k:
    //   a   = softplus(ap)+1e-3
    //   pre = a*x + b
    //   sig = sigmoid(pre);  dsig = sig*(1-sig) = e/(1+e)^2,  e = exp(-|pre|)
    //   x_pre += wexp*sig ;  S += wexp*a*dsig
    // logsumexp(logj) = log(S/wsum) - 0.002   (the two +1e-3 of _logsigmoid)
    float wsum = 0.0f, x_pre = 0.0f, S = 0.0f;
    #pragma unroll
    for (int k = 0; k < KT; ++k) {
        float we = __expf(wl[k]);                       // logits ~N(0,1): no max-shift needed
        wsum += we;
        float t0 = ap[k];
        float e1 = __expf(-fabsf(t0));
        float a  = fmaxf(t0, 0.0f) + __logf(1.0f + e1) + 0.001f;   // _softplus
        float pre = fmaf(a, xv, bp[k]);
        float e  = __expf(-fabsf(pre));
        float r  = __builtin_amdgcn_rcpf(1.0f + e);
        float sig = ((pre >= 0.0f) ? 1.0f : e) * r;
        x_pre = fmaf(we, sig, x_pre);
        S = fmaf(we * a, (e * r) * r, S);
    }
    float invw = __builtin_amdgcn_rcpf(wsum);
    x_pre *= invw;
    float lse = __logf(S * invw) - 0.002f;

    // clip + logit, with fma forms to avoid cancellation near 0/1
    float xc   = fmaf(x_pre, 1.0f - DELTA, 0.5f * DELTA);
    float omxc = fmaf(-(1.0f - DELTA), x_pre, 1.0f - 0.5f * DELTA);  // 1 - xc
    float lxc  = __logf(xc);
    float l1xc = __logf(omxc);

    out[idx]      = lxc - l1xc;                          // xnew
    out[BN + idx] = ld + lse + LOG1MD - (lxc + l1xc);    // logdet_out
}

extern "C" void kernel_launch(void* const* d_in, const int* in_sizes, int n_in,
                              void* d_out, int out_size, void* d_ws, size_t ws_size,
                              hipStream_t stream) {
    const float* x   = (const float*)d_in[0];
    const float* ld  = (const float*)d_in[1];
    const float* dsp = (const float*)d_in[2];
    const float* shp = (const float*)d_in[3];
    float* out = (float*)d_out;

    const int grid = BN / PTS;   // 8192 blocks, exact
    sigmoid_flow_kernel<<<grid, PTS, 0, stream>>>(x, ld, dsp, shp, out);
}